// Round 18
// baseline (62.807 us; speedup 1.0000x reference)
//
#include <hip/hip_runtime.h>
#include <math.h>

#define G  8   // images per block-iteration (one 32-lane group per image)
#define NG 4   // iterations per block -> 32 images/block, grid = 2048 = 8/CU

// ---- int8 dot4: D = c + sum(a.i8[i] * b.i8[i]) -------------------------
#if __has_builtin(__builtin_amdgcn_sdot4)
__device__ __forceinline__ int dot4(unsigned a, unsigned b, int c) {
    return __builtin_amdgcn_sdot4((int)a, (int)b, c, false);
}
#else
__device__ __forceinline__ int dot4(unsigned a, unsigned b, int c) {
    c += (int)(signed char)(a & 255u)         * (int)(signed char)(b & 255u);
    c += (int)(signed char)((a >> 8) & 255u)  * (int)(signed char)((b >> 8) & 255u);
    c += (int)(signed char)((a >> 16) & 255u) * (int)(signed char)((b >> 16) & 255u);
    c += (int)(signed char)(a >> 24)          * (int)(signed char)(b >> 24);
    return c;
}
#endif

// wave-internal LDS fence: orders this wave's LDS ops.
__device__ __forceinline__ void wave_fence() {
    asm volatile("s_waitcnt lgkmcnt(0)" ::: "memory");
}

// LSQ forward scale, bit-exact vs reference: sg = s*g; s_eff = sg + (s - sg)
__device__ __forceinline__ float seff(float s, float gf) {
    float sg = s * gf;
    return sg + (s - sg);
}
// Markstein correctly-rounded f32 division (rs = RN(1/s)), clamp to
// [-128,127] (== clamp-after-round at integer bounds), round-half-even
// via f32 magic-add: low byte of bits(y + 1.5*2^23) is (q & 255).
__device__ __forceinline__ unsigned q8(float v, float s, float rs) {
    float q0 = v * rs;
    float r  = fmaf(-s, q0, v);
    float y  = fmaf(r, rs, q0);          // == RN(v/s)
    y = fminf(fmaxf(y, -128.f), 127.f);
    float t = y + 12582912.0f;           // 1.5*2^23, RNE to integer
    return __float_as_uint(t);           // low byte = q & 255
}
__device__ __forceinline__ unsigned pack4(unsigned a, unsigned b, unsigned c, unsigned d) {
    return (a & 255u) | ((b & 255u) << 8) | ((c & 255u) << 16) | (d << 24);
}
// round-half-even(acc * r) via one f64 fma against 1.5*2^52 magic;
// identical to rint((double)acc*r): boundaries >=1e-8 away, error <=1e-13.
__device__ __forceinline__ int mround(int acc, double r) {
    double t = fma((double)acc, r, 6755399441055744.0);
    return (int)__double_as_longlong(t);     // lo32 = integer (2's complement)
}

// 8-wave-occupancy design: __launch_bounds__(256,8) caps VGPR at 64; all
// register-hungry machinery (async reg staging, skewed pipeline, wide row
// blocks) removed — at 32 waves/CU, thread-level parallelism hides the
// latencies those structures targeted. LDS = 19.8 KB -> 8 blocks/CU.
// x image: 28 rows x 12-dword stride, row = [d0..d3 | d3..d6 | pad4]
// (conflict-free b128 conv1 reads); staging LDS writes stay linear-in-k,
// global addresses permuted (element = row*7 + c8 - (c8>3)).

extern "C" __global__ __launch_bounds__(256, 8)
void qcnn_fused(const float* __restrict__ x,  const float* __restrict__ w1,
                const float* __restrict__ w2, const float* __restrict__ fcw,
                const float* __restrict__ fcb,
                const float* __restrict__ s_in, const float* __restrict__ s_w1,
                const float* __restrict__ s_a1, const float* __restrict__ s_w2,
                const float* __restrict__ s_a2, const float* __restrict__ s_fc,
                float* __restrict__ out, int B,
                float gx, float gw1, float ga1, float gw2, float ga2, float gfc)
{
    __shared__ __align__(16) unsigned xs[G*336];      // quantized x, stride-12 rows
    __shared__ __align__(16) unsigned a1p[G*144];     // conv1 out (4 ic bytes/pixel)
    __shared__ __align__(16) unsigned a2p[G*52];      // conv2 out, padded 52 dw/img
    __shared__ __align__(16) unsigned w1pk[4][5][4];  // per c,ky: EA,EB,OA,OB
    __shared__ unsigned w2p[8][9];                    // per oc,tap: 4 ic bytes
    __shared__ __align__(16) unsigned fcp[10][52];    // fc weights, rows padded to 52
    __shared__ int K2s[8];                            // 128*sum(w2q[oc])
    __shared__ int K3s[10];                           // 128*sum(fcq[o])
    __shared__ float fcbs[10];

    const int tid = threadIdx.x;
    const int g   = tid >> 5;    // image slot (0..7), 2 slots per wave
    const int t   = tid & 31;    // lane within group

    // scales: exact f32 replication (wave-uniform -> SGPRs)
    const float sx  = seff(s_in[0], gx);
    const float sw1 = seff(s_w1[0], gw1);
    const float sa1 = seff(s_a1[0], ga1);
    const float sw2 = seff(s_w2[0], gw2);
    const float sa2 = seff(s_a2[0], ga2);
    const float sfc = seff(s_fc[0], gfc);
    const float rsx = 1.0f / sx;
    const float rw1 = 1.0f / sw1;
    const float rw2 = 1.0f / sw2;
    const float rfc = 1.0f / sfc;
    const double r1 = (double)sx  * (double)sw1 / (double)sa1;
    const double r2 = (double)sa1 * (double)sw2 / (double)sa2;
    const double r3 = (double)sa2 * (double)sfc;

    const long long gbase = (long long)blockIdx.x * NG;

    // per-lane permuted element base + LDS write base (computed once)
    const int c8 = t & 7;
    const int eb = (t >> 3) * 7 + c8 - (c8 > 3 ? 1 : 0);   // global element
    const int db = (t >> 3) * 12 + c8;                     // LDS dword slot

    // ---------------- prep (once per block): weights -> packed i8 ---------
    if (tid < 80) {                       // w1 packs: 4ch x 5ky x 4 variants
        const int c = tid / 20, rem = tid % 20, ky = rem >> 2, vv = rem & 3;
        const float* wr = w1 + c*25 + ky*5;
        unsigned b[5];
        #pragma unroll
        for (int k = 0; k < 5; ++k) b[k] = q8(wr[k], sw1, rw1) & 255u;
        unsigned pk;
        if      (vv == 0) pk = b[0] | (b[1] << 8) | (b[2] << 16) | (b[3] << 24);
        else if (vv == 1) pk = b[4];
        else if (vv == 2) pk = (b[0] << 16) | (b[1] << 24);
        else              pk = b[2] | (b[3] << 8) | (b[4] << 16);
        w1pk[c][ky][vv] = pk;
    } else if (tid < 152) {               // w2 packs: 8oc x 9taps, ic-bytes
        const int d = tid - 80, oc = d / 9, tap = d % 9;
        unsigned pk = 0;
        #pragma unroll
        for (int ic = 0; ic < 4; ++ic)
            pk |= (q8(w2[oc*36 + ic*9 + tap], sw2, rw2) & 255u) << (8*ic);
        w2p[oc][tap] = pk;
    }
    if (tid < 10) fcbs[tid] = fcb[tid];
    for (int i = tid; i < 500; i += 256) { // fc packs: 10 x 50 dwords (rows pad 52)
        const int o = i / 50, kd = i % 50;
        const float* fr = fcw + o*200 + kd*4;
        fcp[o][kd] = pack4(q8(fr[0],sfc,rfc), q8(fr[1],sfc,rfc),
                           q8(fr[2],sfc,rfc), q8(fr[3],sfc,rfc));
    }
    __syncthreads();
    if (tid < 8) {                         // K2[oc] = 128*sum(w2q)
        int s = 0;
        #pragma unroll
        for (int d = 0; d < 9; ++d) s = dot4(w2p[tid][d], 0x01010101u, s);
        K2s[tid] = s << 7;
    } else if (tid < 18) {                 // K3[o] = 128*sum(fcq)
        const int o = tid - 8;
        int s = 0;
        for (int d = 0; d < 50; ++d) s = dot4(fcp[o][d], 0x01010101u, s);
        K3s[o] = s << 7;
    }
    __syncthreads();                       // weights + K2/K3 visible to all

    for (int it = 0; it < NG; ++it) {
        const long long grp = gbase + it;
        if (grp * G >= B) break;
        const bool act = (grp * G + g) < B;

        // ---- stage: load -> quant -> LDS, low-register inline loop ------
        if (act) {
            const float4* xp = (const float4*)x + (grp * G + g) * 196;
            unsigned* dst = &xs[g*336];
            #pragma unroll 2
            for (int k = 0; k < 7; ++k) {
                float4 v = xp[eb + 28*k];
                dst[db + 48*k] = pack4(q8(v.x,sx,rsx), q8(v.y,sx,rsx),
                                       q8(v.z,sx,rsx), q8(v.w,sx,rsx));
            }
        }
        wave_fence();                           // xs (this group) ready

        // ---- conv1: lane = fixed (c,h), y = y0+4k; aligned b128 rows ----
        if (act) {
            const int c  = t & 3;
            const int h  = (t >> 2) & 1;
            const int y0 = t >> 3;                  // 0..3
            uint4 W[5];
            #pragma unroll
            for (int ky = 0; ky < 5; ++ky)
                W[ky] = *(const uint4*)&w1pk[c][ky][0];  // EA,EB,OA,OB
            const unsigned* xb = &xs[g*336];
            #pragma unroll
            for (int k = 0; k < 3; ++k) {
                const int y = y0 + 4*k;
                int acc[6] = {0,0,0,0,0,0};
                #pragma unroll
                for (int ky = 0; ky < 5; ++ky) {
                    const uint4 R = *(const uint4*)&xb[(2*y + ky)*12 + 4*h];
                    acc[0] = dot4(R.y, W[ky].y, dot4(R.x, W[ky].x, acc[0]));
                    acc[1] = dot4(R.y, W[ky].w, dot4(R.x, W[ky].z, acc[1]));
                    acc[2] = dot4(R.z, W[ky].y, dot4(R.y, W[ky].x, acc[2]));
                    acc[3] = dot4(R.z, W[ky].w, dot4(R.y, W[ky].z, acc[3]));
                    acc[4] = dot4(R.w, W[ky].y, dot4(R.z, W[ky].x, acc[4]));
                    acc[5] = dot4(R.w, W[ky].w, dot4(R.z, W[ky].z, acc[5]));
                }
                unsigned char* dst = (unsigned char*)a1p + (g*144 + y*12 + 6*h)*4 + c;
                #pragma unroll
                for (int m = 0; m < 6; ++m) {
                    int q = mround(acc[m], r1);
                    q = min(max(q, 0), 255);
                    dst[4*m] = (unsigned char)(q - 128);
                }
            }
        }
        wave_fence();                           // a1p (this group) ready

        // ---- conv2: per-ky streaming (low live-register count) ----------
        if (act) {
            const int oc = t >> 2;
            unsigned wv[9];
            #pragma unroll
            for (int d = 0; d < 9; ++d) wv[d] = w2p[oc][d];
            const int k2 = K2s[oc];
            const unsigned* base = &a1p[g*144];
            unsigned char* dstb = (unsigned char*)a2p + g*208 + oc*25;
            #pragma unroll
            for (int pass = 0; pass < 2; ++pass) {
                const int y = pass ? 4 : (t & 3);
                if (pass && (t & 3) != 0) break;
                int acc[5] = {k2, k2, k2, k2, k2};
                #pragma unroll
                for (int ky = 0; ky < 3; ++ky) {
                    const uint4* rp = (const uint4*)&base[(2*y + ky)*12];
                    uint4 A = rp[0], Bv = rp[1], Cv = rp[2];
                    const unsigned rw[12] = {A.x,A.y,A.z,A.w,
                                             Bv.x,Bv.y,Bv.z,Bv.w,
                                             Cv.x,Cv.y,Cv.z,Cv.w};
                    #pragma unroll
                    for (int jx = 0; jx < 5; ++jx) {
                        acc[jx] = dot4(rw[2*jx],     wv[ky*3],     acc[jx]);
                        acc[jx] = dot4(rw[2*jx + 1], wv[ky*3 + 1], acc[jx]);
                        acc[jx] = dot4(rw[2*jx + 2], wv[ky*3 + 2], acc[jx]);
                    }
                }
                #pragma unroll
                for (int jx = 0; jx < 5; ++jx) {
                    int q = mround(acc[jx], r2);
                    q = min(max(q, 0), 255);
                    dstb[y*5 + jx] = (unsigned char)(q - 128);
                }
            }
        }
        wave_fence();                           // a2p (this group) ready

        // ---- FC: lane = (o, aligned part {16,16,18} of 50 dwords) -------
        if (act && t < 30) {
            const int part = t / 10;
            const int o    = t - part*10;
            const int k0   = part << 4;            // 0, 16, 32 (16B aligned)
            const unsigned* a2b = &a2p[g*52];
            const uint4* ap = (const uint4*)(a2b + k0);
            const uint4* wp = (const uint4*)(&fcp[o][0] + k0);
            int acc = 0;
            #pragma unroll
            for (int q4 = 0; q4 < 4; ++q4) {
                uint4 a = ap[q4], w = wp[q4];
                acc = dot4(a.x, w.x, acc); acc = dot4(a.y, w.y, acc);
                acc = dot4(a.z, w.z, acc); acc = dot4(a.w, w.w, acc);
            }
            if (part == 2) {
                acc = dot4(a2b[48], fcp[o][48], acc);
                acc = dot4(a2b[49], fcp[o][49], acc);
            }
            const int self0 = (g & 1) * 32 + o;
            const int s1 = __shfl(acc, self0 + 10);
            const int s2 = __shfl(acc, self0 + 20);
            if (part == 0) {
                const int total = acc + s1 + s2 + K3s[o];
                const double oo = (double)total * r3 + (double)fcbs[o];
                out[(grp*G + g)*10 + o] = (float)oo;
            }
        }
        wave_fence();        // a2p reads drained before next iter's conv2
    }
}

extern "C" void kernel_launch(void* const* d_in, const int* in_sizes, int n_in,
                              void* d_out, int out_size, void* d_ws, size_t ws_size,
                              hipStream_t stream) {
    const float* x    = (const float*)d_in[0];
    const float* w1   = (const float*)d_in[1];
    const float* w2   = (const float*)d_in[2];
    const float* fcw  = (const float*)d_in[3];
    const float* fcb  = (const float*)d_in[4];
    const float* s_in = (const float*)d_in[5];
    const float* s_w1 = (const float*)d_in[6];
    const float* s_a1 = (const float*)d_in[7];
    const float* s_w2 = (const float*)d_in[8];
    const float* s_a2 = (const float*)d_in[9];
    const float* s_fc = (const float*)d_in[10];

    const int B = in_sizes[0] / 784;          // 65536
    // grad-scale factors g = 1/sqrt(n*qp), double->float exactly as reference
    const float gx  = (float)(1.0 / sqrt((double)B * 784.0 * 127.0));
    const float gw1 = (float)(1.0 / sqrt(100.0 * 127.0));
    const float ga1 = (float)(1.0 / sqrt((double)B * 576.0 * 255.0));
    const float gw2 = (float)(1.0 / sqrt(288.0 * 127.0));
    const float ga2 = (float)(1.0 / sqrt((double)B * 200.0 * 255.0));
    const float gfc = (float)(1.0 / sqrt(2000.0 * 127.0));

    const int imgs_per_block = G * NG;        // 32
    const int grid = (B + imgs_per_block - 1) / imgs_per_block;   // 2048
    qcnn_fused<<<grid, 256, 0, stream>>>(x, w1, w2, fcw, fcb,
                                         s_in, s_w1, s_a1, s_w2, s_a2, s_fc,
                                         (float*)d_out, B,
                                         gx, gw1, ga1, gw2, ga2, gfc);
}

// Round 19
// 53.403 us; speedup vs baseline: 1.1761x; 1.1761x over previous
//
#include <hip/hip_runtime.h>
#include <math.h>

#define G  8   // images per block-iteration (one 32-lane group per image)
#define NG 8   // iterations per block -> 64 images/block, grid = 1024 = 4/CU

// ---- int8 dot4: D = c + sum(a.i8[i] * b.i8[i]) -------------------------
#if __has_builtin(__builtin_amdgcn_sdot4)
__device__ __forceinline__ int dot4(unsigned a, unsigned b, int c) {
    return __builtin_amdgcn_sdot4((int)a, (int)b, c, false);
}
#else
__device__ __forceinline__ int dot4(unsigned a, unsigned b, int c) {
    c += (int)(signed char)(a & 255u)         * (int)(signed char)(b & 255u);
    c += (int)(signed char)((a >> 8) & 255u)  * (int)(signed char)((b >> 8) & 255u);
    c += (int)(signed char)((a >> 16) & 255u) * (int)(signed char)((b >> 16) & 255u);
    c += (int)(signed char)(a >> 24)          * (int)(signed char)(b >> 24);
    return c;
}
#endif

// wave-internal LDS fence: orders this wave's LDS ops.
__device__ __forceinline__ void wave_fence() {
    asm volatile("s_waitcnt lgkmcnt(0)" ::: "memory");
}

// LSQ forward scale, bit-exact vs reference: sg = s*g; s_eff = sg + (s - sg)
__device__ __forceinline__ float seff(float s, float gf) {
    float sg = s * gf;
    return sg + (s - sg);
}
// Markstein correctly-rounded f32 division (rs = RN(1/s)), clamp to
// [-128,127] (== clamp-after-round at integer bounds), round-half-even
// via f32 magic-add: low byte of bits(y + 1.5*2^23) is (q & 255).
__device__ __forceinline__ unsigned q8(float v, float s, float rs) {
    float q0 = v * rs;
    float r  = fmaf(-s, q0, v);
    float y  = fmaf(r, rs, q0);          // == RN(v/s)
    y = fminf(fmaxf(y, -128.f), 127.f);
    float t = y + 12582912.0f;           // 1.5*2^23, RNE to integer
    return __float_as_uint(t);           // low byte = q & 255
}
__device__ __forceinline__ unsigned pack4(unsigned a, unsigned b, unsigned c, unsigned d) {
    return (a & 255u) | ((b & 255u) << 8) | ((c & 255u) << 16) | (d << 24);
}
// round-half-even(acc * r) via one f64 fma against 1.5*2^52 magic;
// identical to rint((double)acc*r): boundaries >=1e-8 away, error <=1e-13.
__device__ __forceinline__ int mround(int acc, double r) {
    double t = fma((double)acc, r, 6755399441055744.0);
    return (int)__double_as_longlong(t);     // lo32 = integer (2's complement)
}

// x image: 28 rows x 12-dword stride, row = [d0 d1 d2 d3 | d3 d4 d5 d6 | pad4].
// Stride 12 (48B) makes conv1's per-instruction bank set {72*y0+4h} mod 32
// fully distinct (kills the old stride-8 4-way conflict); cross-group (336
// dwords = 16 mod 32) is a free 2-way. Staging keeps LINEAR-in-k LDS writes:
// slot w=t+32k -> LDS idx (t>>3)*12+(t&7) + 48k; GLOBAL addresses permuted
// (element = row*7 + c8 - (c8>3), dup col3 loaded twice from global).
// Skewed pipeline: conv1(it) | conv2(it-1) | FC(it-2), 1 fence/iter.

extern "C" __global__ __launch_bounds__(256, 4)
void qcnn_fused(const float* __restrict__ x,  const float* __restrict__ w1,
                const float* __restrict__ w2, const float* __restrict__ fcw,
                const float* __restrict__ fcb,
                const float* __restrict__ s_in, const float* __restrict__ s_w1,
                const float* __restrict__ s_a1, const float* __restrict__ s_w2,
                const float* __restrict__ s_a2, const float* __restrict__ s_fc,
                float* __restrict__ out, int B,
                float gx, float gw1, float ga1, float gw2, float ga2, float gfc)
{
    __shared__ __align__(16) unsigned xs[2][G*336];   // dbuf quantized x, stride-12 rows
    __shared__ __align__(16) unsigned a1p[2][G*144];  // dbuf conv1 out (4 ic bytes/pixel)
    __shared__ __align__(16) unsigned a2p[2][G*52];   // dbuf conv2 out, padded 52 dw/img
    __shared__ __align__(16) unsigned w1pk[4][5][4];  // per c,ky: EA,EB,OA,OB
    __shared__ unsigned w2p[8][9];                    // per oc,tap: 4 ic bytes
    __shared__ __align__(16) unsigned fcp[10][52];    // fc weights, rows padded to 52
    __shared__ int K2s[8];                            // 128*sum(w2q[oc])
    __shared__ int K3s[10];                           // 128*sum(fcq[o])
    __shared__ float fcbs[10];

    const int tid = threadIdx.x;
    const int g   = tid >> 5;    // image slot (0..7), 2 slots per wave
    const int t   = tid & 31;    // lane within group

    // scales: exact f32 replication of reference forward values
    const float sx  = seff(s_in[0], gx);
    const float sw1 = seff(s_w1[0], gw1);
    const float sa1 = seff(s_a1[0], ga1);
    const float sw2 = seff(s_w2[0], gw2);
    const float sa2 = seff(s_a2[0], ga2);
    const float sfc = seff(s_fc[0], gfc);
    const float rsx = 1.0f / sx;
    const float rw1 = 1.0f / sw1;
    const float rw2 = 1.0f / sw2;
    const float rfc = 1.0f / sfc;
    const double r1 = (double)sx  * (double)sw1 / (double)sa1;
    const double r2 = (double)sa1 * (double)sw2 / (double)sa2;
    const double r3 = (double)sa2 * (double)sfc;

    const long long gbase = (long long)blockIdx.x * NG;

    // per-lane permuted element base + LDS write base (computed once)
    const int c8 = t & 7;
    const int eb = (t >> 3) * 7 + c8 - (c8 > 3 ? 1 : 0);   // global element
    const int db = (t >> 3) * 12 + c8;                     // LDS dword slot

    // ---- group-local async staging: issue loads early, write late -------
    float4 Rv0, Rv1, Rv2, Rv3, Rv4, Rv5, Rv6;
    auto stage_load = [&](long long grp) {
        const long long img = grp * G + g;
        if (img >= B) return;
        const float4* xp = (const float4*)x + img * 196;
        Rv0 = xp[eb];        Rv1 = xp[eb + 28];  Rv2 = xp[eb + 56];
        Rv3 = xp[eb + 84];   Rv4 = xp[eb + 112]; Rv5 = xp[eb + 140];
        Rv6 = xp[eb + 168];
    };
    auto stage_write = [&](long long grp, int buf) {
        const long long img = grp * G + g;
        if (img >= B) return;
        unsigned* dst = &xs[buf][g*336];
        float4 v;
        v = Rv0; dst[db]       = pack4(q8(v.x,sx,rsx), q8(v.y,sx,rsx), q8(v.z,sx,rsx), q8(v.w,sx,rsx));
        v = Rv1; dst[db + 48]  = pack4(q8(v.x,sx,rsx), q8(v.y,sx,rsx), q8(v.z,sx,rsx), q8(v.w,sx,rsx));
        v = Rv2; dst[db + 96]  = pack4(q8(v.x,sx,rsx), q8(v.y,sx,rsx), q8(v.z,sx,rsx), q8(v.w,sx,rsx));
        v = Rv3; dst[db + 144] = pack4(q8(v.x,sx,rsx), q8(v.y,sx,rsx), q8(v.z,sx,rsx), q8(v.w,sx,rsx));
        v = Rv4; dst[db + 192] = pack4(q8(v.x,sx,rsx), q8(v.y,sx,rsx), q8(v.z,sx,rsx), q8(v.w,sx,rsx));
        v = Rv5; dst[db + 240] = pack4(q8(v.x,sx,rsx), q8(v.y,sx,rsx), q8(v.z,sx,rsx), q8(v.w,sx,rsx));
        v = Rv6; dst[db + 288] = pack4(q8(v.x,sx,rsx), q8(v.y,sx,rsx), q8(v.z,sx,rsx), q8(v.w,sx,rsx));
    };

    // start group-0 x loads before anything else (HBM latency under prep)
    stage_load(gbase);

    // ---------------- prep (once per block): weights -> packed i8 ---------
    if (tid < 80) {                       // w1 packs: 4ch x 5ky x 4 variants
        const int c = tid / 20, rem = tid % 20, ky = rem >> 2, vv = rem & 3;
        const float* wr = w1 + c*25 + ky*5;
        unsigned b[5];
        #pragma unroll
        for (int k = 0; k < 5; ++k) b[k] = q8(wr[k], sw1, rw1) & 255u;
        unsigned pk;
        if      (vv == 0) pk = b[0] | (b[1] << 8) | (b[2] << 16) | (b[3] << 24);
        else if (vv == 1) pk = b[4];
        else if (vv == 2) pk = (b[0] << 16) | (b[1] << 24);
        else              pk = b[2] | (b[3] << 8) | (b[4] << 16);
        w1pk[c][ky][vv] = pk;
    } else if (tid < 152) {               // w2 packs: 8oc x 9taps, ic-bytes
        const int d = tid - 80, oc = d / 9, tap = d % 9;
        unsigned pk = 0;
        #pragma unroll
        for (int ic = 0; ic < 4; ++ic)
            pk |= (q8(w2[oc*36 + ic*9 + tap], sw2, rw2) & 255u) << (8*ic);
        w2p[oc][tap] = pk;
    }
    if (tid < 10) fcbs[tid] = fcb[tid];
    for (int i = tid; i < 500; i += 256) { // fc packs: 10 x 50 dwords (rows pad 52)
        const int o = i / 50, kd = i % 50;
        const float* fr = fcw + o*200 + kd*4;
        fcp[o][kd] = pack4(q8(fr[0],sfc,rfc), q8(fr[1],sfc,rfc),
                           q8(fr[2],sfc,rfc), q8(fr[3],sfc,rfc));
    }
    __syncthreads();
    if (tid < 8) {                         // K2[oc] = 128*sum(w2q)
        int s = 0;
        #pragma unroll
        for (int d = 0; d < 9; ++d) s = dot4(w2p[tid][d], 0x01010101u, s);
        K2s[tid] = s << 7;
    } else if (tid < 18) {                 // K3[o] = 128*sum(fcq)
        const int o = tid - 8;
        int s = 0;
        for (int d = 0; d < 50; ++d) s = dot4(fcp[o][d], 0x01010101u, s);
        K3s[o] = s << 7;
    }
    __syncthreads();                       // weights + K2/K3 visible to all
    stage_write(gbase, 0);
    wave_fence();                          // xs[0] (this group) ready

    // ---- skewed pipeline: conv1(it) | conv2(it-1) | FC(it-2), 1 fence ----
    for (int it = 0; it < NG + 2; ++it) {
        const long long grp = gbase + it;

        if (it + 1 < NG) stage_load(grp + 1);   // issue loads, no wait

        // ---- conv1(it): lane = (c,h,y0), y = 3y0..3y0+2, streamed rows --
        // rows 6y0..6y0+8 read ONCE (9 b128 vs 15): row j serves y=3y0+i
        // when ky = j-2i in [0,4].
        if (it < NG && (grp * G + g) < B) {
            const int c  = t & 3;
            const int h  = (t >> 2) & 1;
            const int y0 = t >> 3;                  // 0..3
            uint4 W[5];
            #pragma unroll
            for (int ky = 0; ky < 5; ++ky)
                W[ky] = *(const uint4*)&w1pk[c][ky][0];  // EA,EB,OA,OB
            const unsigned* xb = &xs[it & 1][g*336 + y0*72 + 4*h];
            unsigned char* a1b = (unsigned char*)&a1p[it & 1][0];
            int aA[6] = {0,0,0,0,0,0};
            int aB[6] = {0,0,0,0,0,0};
            int aC[6] = {0,0,0,0,0,0};
#define APPLY(A, Wk, R) \
            A[0] = dot4(R.y, Wk.y, dot4(R.x, Wk.x, A[0])); \
            A[1] = dot4(R.y, Wk.w, dot4(R.x, Wk.z, A[1])); \
            A[2] = dot4(R.z, Wk.y, dot4(R.y, Wk.x, A[2])); \
            A[3] = dot4(R.z, Wk.w, dot4(R.y, Wk.z, A[3])); \
            A[4] = dot4(R.w, Wk.y, dot4(R.z, Wk.x, A[4])); \
            A[5] = dot4(R.w, Wk.w, dot4(R.z, Wk.z, A[5]))
#define EPI(A, yy) { \
            unsigned char* dst = a1b + (g*144 + (yy)*12 + 6*h)*4 + c; \
            _Pragma("unroll") \
            for (int m = 0; m < 6; ++m) { \
                int q = mround(A[m], r1); \
                q = min(max(q, 0), 255); \
                dst[4*m] = (unsigned char)(q - 128); } }
            uint4 R;
            R = *(const uint4*)&xb[0];   APPLY(aA, W[0], R);
            R = *(const uint4*)&xb[12];  APPLY(aA, W[1], R);
            R = *(const uint4*)&xb[24];  APPLY(aA, W[2], R); APPLY(aB, W[0], R);
            R = *(const uint4*)&xb[36];  APPLY(aA, W[3], R); APPLY(aB, W[1], R);
            R = *(const uint4*)&xb[48];  APPLY(aA, W[4], R); APPLY(aB, W[2], R); APPLY(aC, W[0], R);
            EPI(aA, 3*y0);
            R = *(const uint4*)&xb[60];  APPLY(aB, W[3], R); APPLY(aC, W[1], R);
            R = *(const uint4*)&xb[72];  APPLY(aB, W[4], R); APPLY(aC, W[2], R);
            EPI(aB, 3*y0 + 1);
            R = *(const uint4*)&xb[84];  APPLY(aC, W[3], R);
            R = *(const uint4*)&xb[96];  APPLY(aC, W[4], R);
            EPI(aC, 3*y0 + 2);
#undef APPLY
#undef EPI
        }

        // ---- conv2(it-1): a1p[(it-1)&1] -> a2p[(it-1)&1] ----------------
        if (it >= 1 && it <= NG && ((grp - 1) * G + g) < B) {
            const int oc = t >> 2;
            unsigned wv[9];
            #pragma unroll
            for (int d = 0; d < 9; ++d) wv[d] = w2p[oc][d];
            const int k2 = K2s[oc];
            const unsigned* base = &a1p[(it - 1) & 1][g*144];
            unsigned char* dstb = (unsigned char*)&a2p[(it - 1) & 1][0] + g*208 + oc*25;
            #pragma unroll
            for (int pass = 0; pass < 2; ++pass) {
                const int y = pass ? 4 : (t & 3);
                if (pass && (t & 3) != 0) break;
                unsigned rw[3][12];
                #pragma unroll
                for (int ky = 0; ky < 3; ++ky) {
                    const uint4* rp = (const uint4*)&base[(2*y + ky)*12];
                    uint4 A = rp[0], Bv = rp[1], Cv = rp[2];
                    rw[ky][0]=A.x;  rw[ky][1]=A.y;  rw[ky][2]=A.z;  rw[ky][3]=A.w;
                    rw[ky][4]=Bv.x; rw[ky][5]=Bv.y; rw[ky][6]=Bv.z; rw[ky][7]=Bv.w;
                    rw[ky][8]=Cv.x; rw[ky][9]=Cv.y; rw[ky][10]=Cv.z; rw[ky][11]=Cv.w;
                }
                #pragma unroll
                for (int jx = 0; jx < 5; ++jx) {
                    int acc = k2;
                    #pragma unroll
                    for (int ky = 0; ky < 3; ++ky)
                        #pragma unroll
                        for (int kx = 0; kx < 3; ++kx)
                            acc = dot4(rw[ky][2*jx + kx], wv[ky*3 + kx], acc);
                    int q = mround(acc, r2);
                    q = min(max(q, 0), 255);
                    dstb[y*5 + jx] = (unsigned char)(q - 128);
                }
            }
        }

        // ---- FC(it-2): a2p[it&1] -> out; aligned b128 parts {16,16,18} --
        if (it >= 2 && ((grp - 2) * G + g) < B && t < 30) {
            const int part = t / 10;
            const int o    = t - part*10;
            const int k0   = part << 4;            // 0, 16, 32 (16B aligned)
            const unsigned* a2b = &a2p[it & 1][g*52];
            const uint4* ap = (const uint4*)(a2b + k0);
            const uint4* wp = (const uint4*)(&fcp[o][0] + k0);
            int acc = 0;
            #pragma unroll
            for (int q4 = 0; q4 < 4; ++q4) {
                uint4 a = ap[q4], w = wp[q4];
                acc = dot4(a.x, w.x, acc); acc = dot4(a.y, w.y, acc);
                acc = dot4(a.z, w.z, acc); acc = dot4(a.w, w.w, acc);
            }
            if (part == 2) {
                acc = dot4(a2b[48], fcp[o][48], acc);
                acc = dot4(a2b[49], fcp[o][49], acc);
            }
            const int self0 = (g & 1) * 32 + o;
            const int s1 = __shfl(acc, self0 + 10);
            const int s2 = __shfl(acc, self0 + 20);
            if (part == 0) {
                const int total = acc + s1 + s2 + K3s[o];
                const double oo = (double)total * r3 + (double)fcbs[o];
                out[((grp - 2)*G + g)*10 + o] = (float)oo;
            }
        }

        if (it + 1 < NG) stage_write(grp + 1, (it + 1) & 1);

        wave_fence();   // single drain: all this iteration's LDS ops done
    }
}

extern "C" void kernel_launch(void* const* d_in, const int* in_sizes, int n_in,
                              void* d_out, int out_size, void* d_ws, size_t ws_size,
                              hipStream_t stream) {
    const float* x    = (const float*)d_in[0];
    const float* w1   = (const float*)d_in[1];
    const float* w2   = (const float*)d_in[2];
    const float* fcw  = (const float*)d_in[3];
    const float* fcb  = (const float*)d_in[4];
    const float* s_in = (const float*)d_in[5];
    const float* s_w1 = (const float*)d_in[6];
    const float* s_a1 = (const float*)d_in[7];
    const float* s_w2 = (const float*)d_in[8];
    const float* s_a2 = (const float*)d_in[9];
    const float* s_fc = (const float*)d_in[10];

    const int B = in_sizes[0] / 784;          // 65536
    // grad-scale factors g = 1/sqrt(n*qp), double->float exactly as reference
    const float gx  = (float)(1.0 / sqrt((double)B * 784.0 * 127.0));
    const float gw1 = (float)(1.0 / sqrt(100.0 * 127.0));
    const float ga1 = (float)(1.0 / sqrt((double)B * 576.0 * 255.0));
    const float gw2 = (float)(1.0 / sqrt(288.0 * 127.0));
    const float ga2 = (float)(1.0 / sqrt((double)B * 200.0 * 255.0));
    const float gfc = (float)(1.0 / sqrt(2000.0 * 127.0));

    const int imgs_per_block = G * NG;        // 64
    const int grid = (B + imgs_per_block - 1) / imgs_per_block;   // 1024
    qcnn_fused<<<grid, 256, 0, stream>>>(x, w1, w2, fcw, fcb,
                                         s_in, s_w1, s_a1, s_w2, s_a2, s_fc,
                                         (float*)d_out, B,
                                         gx, gw1, ga1, gw2, ga2, gfc);
}